// Round 9
// baseline (145.923 us; speedup 1.0000x reference)
//
#include <hip/hip_runtime.h>

#define NN 4096
#define TSTEPS 8
#define EPSW 1e-12f
#define SLABW 512
#define NSLAB 8
#define LSLAB 9
#define BUCKET 64
#define LBUCK 6
#define SLAB_ELEMS ((size_t)NN * SLABW)  // 2^21

typedef unsigned int uint32;
typedef uint32 uint4v __attribute__((ext_vector_type(4)));
typedef float f32x2 __attribute__((ext_vector_type(2)));

__device__ __forceinline__ uint32 bf16rn(float f) {
  uint32 b = __float_as_uint(f);
  return (b + 0x7FFFu + ((b >> 16) & 1u)) >> 16;
}
__device__ __forceinline__ float bf2f(ushort u) {
  return __uint_as_float(((uint32)u) << 16);
}
// XOR-swizzle of 8-float blocks for the m2 LDS accumulator.
__device__ __forceinline__ int sphys(int c) {
  int blk = c >> 3;
  return ((blk ^ ((blk >> 3) & 7)) << 3) | (c & 7);
}

// ---------------------------------------------------------------------------
// Pass 1: column degree sums (deg pre-zeroed)
// ---------------------------------------------------------------------------
__global__ __launch_bounds__(256) void deg_kernel(
    const int* __restrict__ cols, const float* __restrict__ ew,
    float* __restrict__ deg, int E) {
  int e = blockIdx.x * 256 + threadIdx.x;
  if (e >= E) return;
  atomicAdd(deg + cols[e], ew[e]);
}

// Pass 2: bucket scatter (fixed 64-slot rows), normalized weights.
// fill pre-zeroed. Rows Poisson(16): P(deg>64) ~ 1e-18, clamp deterministic.
__global__ __launch_bounds__(256) void scatter_kernel(
    const int* __restrict__ rows, const int* __restrict__ cols,
    const float* __restrict__ ew, const float* __restrict__ deg,
    int* __restrict__ fill, int* __restrict__ col_s, float* __restrict__ w_s,
    int E) {
  int e = blockIdx.x * 256 + threadIdx.x;
  if (e >= E) return;
  int r = rows[e], c = cols[e];
  float w = ew[e] / fmaxf(deg[c], EPSW);
  int pos = atomicAdd(fill + r, 1);
  if (pos < BUCKET) {
    col_s[(r << LBUCK) + pos] = c;
    w_s[(r << LBUCK) + pos] = w;
  }
}

// ---------------------------------------------------------------------------
// M2 = M*M from buckets. One wave per row, dense fp32 LDS accumulator
// (swizzled). Inner gather: 4 edges concurrently in 16-lane groups (__shfl),
// fill[] vector-prefetched. Fused diag1 (self-loops, wave reduce) + diag2.
// ---------------------------------------------------------------------------
__global__ __launch_bounds__(64) void m2_csr_kernel(
    const int* __restrict__ fill, const int* __restrict__ col_s,
    const float* __restrict__ w_s, ushort* __restrict__ dst,
    float* __restrict__ diags) {
  int i = blockIdx.x;
  int tid = threadIdx.x;
  __shared__ float acc[NN];
  float4 z4 = make_float4(0.f, 0.f, 0.f, 0.f);
#pragma unroll
  for (int k = 0; k < 16; ++k) *(float4*)(acc + k * 256 + tid * 4) = z4;
  int cnt = min(fill[i], BUCKET);
  __syncthreads();
  int myc = 0, fj = 0;
  float myw = 0.f;
  if (tid < cnt) {
    myc = col_s[(i << LBUCK) + tid];
    myw = w_s[(i << LBUCK) + tid];
    fj = min(fill[myc], BUCKET);  // parallel vector prefetch
  }
  // diag1 = sum of self-loop weights (handles duplicates)
  float sl = (tid < cnt && myc == i) ? myw : 0.f;
#pragma unroll
  for (int o = 32; o; o >>= 1) sl += __shfl_down(sl, o);
  if (tid == 0) diags[i] = sl;

  int g = tid >> 4, f0 = tid & 15;
  for (int e = 0; e < cnt; e += 4) {
    int idx = e + g;
    bool v = idx < cnt;
    int srcl = v ? idx : 0;
    int j = __shfl(myc, srcl);
    float we = __shfl(myw, srcl);
    int fc = __shfl(fj, srcl);
    if (v) {
      for (int f = f0; f < fc; f += 16)
        atomicAdd(acc + sphys(col_s[(j << LBUCK) + f]),
                  we * w_s[(j << LBUCK) + f]);
    }
  }
  __syncthreads();
  if (tid == 0) diags[NN + i] = acc[sphys(i)];
#pragma unroll
  for (int p = 0; p < 8; ++p) {
    int c = p * SLABW + tid * 8;
    int ph = sphys(c);
    float4 lo = *(const float4*)(acc + ph);
    float4 hi = *(const float4*)(acc + ph + 4);
    uint4v o;
    o.x = bf16rn(lo.x) | (bf16rn(lo.y) << 16);
    o.y = bf16rn(lo.z) | (bf16rn(lo.w) << 16);
    o.z = bf16rn(hi.x) | (bf16rn(hi.y) << 16);
    o.w = bf16rn(hi.z) | (bf16rn(hi.w) << 16);
    *(uint4v*)(dst + (size_t)p * SLAB_ELEMS + (size_t)i * SLABW + tid * 8) = o;
  }
}

// ---------------------------------------------------------------------------
// SpMM: 256-thr blocks = 4 waves x 4 rows, same slab (XCD L2 affinity).
// Per-wave private LDS edge staging (no barriers). 16-deep load batch covers
// the average row in ONE latency wait; 8/4/1 tails.
// ---------------------------------------------------------------------------
#define FMA8(u, wv)                                          \
  do {                                                       \
    f32x2 w2_ = {(wv), (wv)};                                \
    _Pragma("unroll") for (int q = 0; q < 4; ++q) {          \
      f32x2 p_;                                              \
      p_.x = __uint_as_float((u)[q] << 16);                  \
      p_.y = __uint_as_float((u)[q] & 0xFFFF0000u);          \
      acc2[q] = p_ * w2_ + acc2[q];                          \
    }                                                        \
  } while (0)

__global__ __launch_bounds__(256) void spmm_kernel(
    const ushort* __restrict__ src, ushort* __restrict__ dst,
    const int* __restrict__ fill, const int* __restrict__ col_s,
    const float* __restrict__ w_s, float* __restrict__ diags, int tIdx) {
  int b = blockIdx.x;
  int slab = b & (NSLAB - 1);
  int wv = threadIdx.x >> 6;
  int lane = threadIdx.x & 63;
  int i = ((b >> 3) << 2) | wv;
  int cnt = min(fill[i], BUCKET);
  __shared__ int sc_all[4][64];
  __shared__ float sw_all[4][64];
  int* sc = sc_all[wv];
  float* sw = sw_all[wv];
  f32x2 acc2[4];
#pragma unroll
  for (int q = 0; q < 4; ++q) acc2[q] = (f32x2){0.f, 0.f};
  const ushort* sbase = src + (size_t)slab * SLAB_ELEMS + lane * 8;

  if (lane < cnt) {
    sc[lane] = col_s[(i << LBUCK) + lane];
    sw[lane] = w_s[(i << LBUCK) + lane];
  }
  // no __syncthreads: producer wave == consumer wave (lgkmcnt ordering)
  int k = 0;
  for (; k + 16 <= cnt; k += 16) {
    uint4v u[16];
    float wl[16];
#pragma unroll
    for (int t = 0; t < 16; ++t) u[t] = *(const uint4v*)(sbase + ((size_t)sc[k + t] << LSLAB));
#pragma unroll
    for (int t = 0; t < 16; ++t) wl[t] = sw[k + t];
#pragma unroll
    for (int t = 0; t < 16; ++t) FMA8(u[t], wl[t]);
  }
  for (; k + 8 <= cnt; k += 8) {
    uint4v u[8];
    float wl[8];
#pragma unroll
    for (int t = 0; t < 8; ++t) u[t] = *(const uint4v*)(sbase + ((size_t)sc[k + t] << LSLAB));
#pragma unroll
    for (int t = 0; t < 8; ++t) wl[t] = sw[k + t];
#pragma unroll
    for (int t = 0; t < 8; ++t) FMA8(u[t], wl[t]);
  }
  for (; k + 4 <= cnt; k += 4) {
    uint4v u[4];
    float wl[4];
#pragma unroll
    for (int t = 0; t < 4; ++t) u[t] = *(const uint4v*)(sbase + ((size_t)sc[k + t] << LSLAB));
#pragma unroll
    for (int t = 0; t < 4; ++t) wl[t] = sw[k + t];
#pragma unroll
    for (int t = 0; t < 4; ++t) FMA8(u[t], wl[t]);
  }
  for (; k < cnt; ++k) {
    uint4v u = *(const uint4v*)(sbase + ((size_t)sc[k] << LSLAB));
    float w = sw[k];
    FMA8(u, w);
  }

  uint4v o;
#pragma unroll
  for (int q = 0; q < 4; ++q)
    o[q] = bf16rn(acc2[q].x) | (bf16rn(acc2[q].y) << 16);
  *(uint4v*)(dst + (size_t)slab * SLAB_ELEMS + (size_t)i * SLABW + lane * 8) = o;

  if ((i >> LSLAB) == slab) {
    int lc = i & (SLABW - 1);
    if ((lc >> 3) == lane) {
      int m = lc & 7;
      f32x2 pr = acc2[m >> 1];
      float v = (m & 1) ? pr.y : pr.x;
      diags[tIdx * NN + i] = v;
    }
  }
}

// ---------------------------------------------------------------------------
// Trace products -> PARTIALS (no atomics): part[(v*8+jc)*NN + gi].
// diag5 = <M2,M3^T>, diag6 = <M3,M3^T>, diag7 = <M3,M4^T>, diag8 = <M4,M4^T>.
// ---------------------------------------------------------------------------
__device__ __forceinline__ size_t slab_addr(int row, int col) {
  return ((size_t)(col >> LSLAB)) * SLAB_ELEMS + (size_t)row * SLABW + (col & (SLABW - 1));
}
__device__ __forceinline__ float elem8(uint4v lo, uint4v hi, int c) {
  uint32 u = (c < 8) ? lo[(c & 7) >> 1] : hi[(c & 7) >> 1];
  return __uint_as_float((c & 1) ? (u & 0xFFFF0000u) : (u << 16));
}

__global__ __launch_bounds__(256) void trace_kernel(
    const ushort* __restrict__ M2, const ushort* __restrict__ M3,
    const ushort* __restrict__ M4, float* __restrict__ part) {
  int bid = blockIdx.x;
  int bi = bid >> 3, jc = bid & 7;
  int tid = threadIdx.x;
  __shared__ ushort b3[64 * 64], b4[64 * 64];
  __shared__ float red[4][4][64];
  int lr = tid >> 2, lc0 = (tid & 3) * 16;
  int r = tid & 63, jq = tid >> 6;
  float s5 = 0.f, s6 = 0.f, s7 = 0.f, s8 = 0.f;

  for (int it = 0; it < 8; ++it) {
    int bj = jc * 8 + it;
    {
      int gj = bj * 64 + lr;
      int gc = bi * 64 + lc0;
      size_t base = slab_addr(gj, gc);
      uint4v v3a = *(const uint4v*)(M3 + base);
      uint4v v3b = *(const uint4v*)(M3 + base + 8);
      uint4v v4a = *(const uint4v*)(M4 + base);
      uint4v v4b = *(const uint4v*)(M4 + base + 8);
      int cb0 = (lc0 >> 3) ^ (lr & 7);
      int cb1 = ((lc0 >> 3) + 1) ^ (lr & 7);
      *(uint4v*)(b3 + lr * 64 + cb0 * 8) = v3a;
      *(uint4v*)(b3 + lr * 64 + cb1 * 8) = v3b;
      *(uint4v*)(b4 + lr * 64 + cb0 * 8) = v4a;
      *(uint4v*)(b4 + lr * 64 + cb1 * 8) = v4b;
    }
    __syncthreads();
    int gi = bi * 64 + r;
    int gc0 = bj * 64 + jq * 16;
    size_t abase = slab_addr(gi, gc0);
    uint4v a2a = *(const uint4v*)(M2 + abase);
    uint4v a2b = *(const uint4v*)(M2 + abase + 8);
    uint4v a3a = *(const uint4v*)(M3 + abase);
    uint4v a3b = *(const uint4v*)(M3 + abase + 8);
    uint4v a4a = *(const uint4v*)(M4 + abase);
    uint4v a4b = *(const uint4v*)(M4 + abase + 8);
#pragma unroll
    for (int c = 0; c < 16; ++c) {
      int jj = jq * 16 + c;
      int idx = jj * 64 + ((((r >> 3) ^ (jj & 7)) << 3) | (r & 7));
      float bv3 = bf2f(b3[idx]);
      float bv4 = bf2f(b4[idx]);
      float av2 = elem8(a2a, a2b, c);
      float av3 = elem8(a3a, a3b, c);
      float av4 = elem8(a4a, a4b, c);
      s5 += av2 * bv3;
      s6 += av3 * bv3;
      s7 += av3 * bv4;
      s8 += av4 * bv4;
    }
    __syncthreads();
  }
  red[0][jq][r] = s5;
  red[1][jq][r] = s6;
  red[2][jq][r] = s7;
  red[3][jq][r] = s8;
  __syncthreads();
  if (tid < 64) {
    int gi = bi * 64 + tid;
#pragma unroll
    for (int v = 0; v < 4; ++v) {
      float s = red[v][0][tid] + red[v][1][tid] + red[v][2][tid] + red[v][3][tid];
      part[((size_t)v * 8 + jc) * NN + gi] = s;
    }
  }
}

// ---------------------------------------------------------------------------
// Finalize: X = [ones, diag_1..diag_8], standardize each column (ddof=0).
// k<=4 read diags rows 0..3; k>=5 reduce 8 trace partials.
// ---------------------------------------------------------------------------
__global__ __launch_bounds__(256) void finalize_kernel(
    const float* __restrict__ diags, const float* __restrict__ part,
    float* __restrict__ out) {
  int k = blockIdx.x;  // 0..8
  int tid = threadIdx.x;
  float vals[16];
  float sum = 0.f, sq = 0.f;
#pragma unroll
  for (int j = 0; j < 16; ++j) {
    int i = j * 256 + tid;
    float v;
    if (k == 0) {
      v = 1.0f;
    } else if (k <= 4) {
      v = diags[(size_t)(k - 1) * NN + i];
    } else {
      v = 0.f;
      const float* p = part + (size_t)(k - 5) * 8 * NN + i;
#pragma unroll
      for (int jc = 0; jc < 8; ++jc) v += p[(size_t)jc * NN];
    }
    vals[j] = v;
    sum += v;
    sq += v * v;
  }
#pragma unroll
  for (int off = 32; off; off >>= 1) {
    sum += __shfl_down(sum, off);
    sq += __shfl_down(sq, off);
  }
  __shared__ float s0[4], s1[4];
  __shared__ float smean, sinv;
  int wid = tid >> 6, lane = tid & 63;
  if (lane == 0) { s0[wid] = sum; s1[wid] = sq; }
  __syncthreads();
  if (tid == 0) {
    float S = s0[0] + s0[1] + s0[2] + s0[3];
    float Q = s1[0] + s1[1] + s1[2] + s1[3];
    float mean = S / (float)NN;
    float var = Q / (float)NN - mean * mean;
    var = fmaxf(var, 0.f);
    float sd = fmaxf(sqrtf(var), 1e-6f);
    smean = mean;
    sinv = 1.f / sd;
  }
  __syncthreads();
#pragma unroll
  for (int j = 0; j < 16; ++j) {
    int i = j * 256 + tid;
    out[i * (TSTEPS + 1) + k] = (vals[j] - smean) * sinv;
  }
}

// ---------------------------------------------------------------------------
// Host driver: 8 graph nodes.
// ---------------------------------------------------------------------------
extern "C" void kernel_launch(void* const* d_in, const int* in_sizes, int n_in,
                              void* d_out, int out_size, void* d_ws, size_t ws_size,
                              hipStream_t stream) {
  const int* ei = (const int*)d_in[0];
  const float* ew = (const float*)d_in[1];
  int E = in_sizes[1];
  const int* rows = ei;
  const int* cols = ei + E;

  char* ws = (char*)d_ws;
  size_t off = 0;
  auto alloc = [&](size_t bytes) {
    void* p = ws + off;
    off = (off + bytes + 255) & ~(size_t)255;
    return p;
  };
  // contiguous zero region: deg | fill (one tiny memset)
  float* deg   = (float*)alloc(NN * 4);
  int*   fill  = (int*)alloc(NN * 4);
  size_t zbytes = off;
  float* diags = (float*)alloc((size_t)4 * NN * 4);       // rows 0..3 (t=1..4)
  float* part  = (float*)alloc((size_t)4 * 8 * NN * 4);   // trace partials
  int*   col_s = (int*)alloc((size_t)NN * BUCKET * 4);
  float* w_s   = (float*)alloc((size_t)NN * BUCKET * 4);
  ushort* bufA = (ushort*)alloc((size_t)NN * NN * 2);  // M2
  ushort* bufB = (ushort*)alloc((size_t)NN * NN * 2);  // M3
  ushort* bufC = (ushort*)alloc((size_t)NN * NN * 2);  // M4

  hipMemsetAsync(deg, 0, zbytes, stream);

  int eb = (E + 255) / 256;
  deg_kernel<<<eb, 256, 0, stream>>>(cols, ew, deg, E);
  scatter_kernel<<<eb, 256, 0, stream>>>(rows, cols, ew, deg, fill, col_s, w_s, E);

  m2_csr_kernel<<<NN, 64, 0, stream>>>(fill, col_s, w_s, bufA, diags);
  spmm_kernel<<<(NN / 4) * NSLAB, 256, 0, stream>>>(bufA, bufB, fill, col_s, w_s, diags, 2);
  spmm_kernel<<<(NN / 4) * NSLAB, 256, 0, stream>>>(bufB, bufC, fill, col_s, w_s, diags, 3);
  trace_kernel<<<512, 256, 0, stream>>>(bufA, bufB, bufC, part);

  finalize_kernel<<<TSTEPS + 1, 256, 0, stream>>>(diags, part, (float*)d_out);
}

// Round 10
// 133.478 us; speedup vs baseline: 1.0932x; 1.0932x over previous
//
#include <hip/hip_runtime.h>

#define NN 4096
#define TSTEPS 8
#define EPSW 1e-12f
#define SLABW 512
#define NSLAB 8
#define LSLAB 9
#define BUCKET 64
#define LBUCK 6
#define SLAB_ELEMS ((size_t)NN * SLABW)  // 2^21

typedef unsigned int uint32;
typedef uint32 uint4v __attribute__((ext_vector_type(4)));
typedef float f32x2 __attribute__((ext_vector_type(2)));

__device__ __forceinline__ uint32 bf16rn(float f) {
  uint32 b = __float_as_uint(f);
  return (b + 0x7FFFu + ((b >> 16) & 1u)) >> 16;
}
__device__ __forceinline__ float bf2f(ushort u) {
  return __uint_as_float(((uint32)u) << 16);
}
// XOR-swizzle of 8-float blocks for the m2 LDS accumulator.
__device__ __forceinline__ int sphys(int c) {
  int blk = c >> 3;
  return ((blk ^ ((blk >> 3) & 7)) << 3) | (c & 7);
}

// ---------------------------------------------------------------------------
// Pass 1: column degree sums (deg pre-zeroed)
// ---------------------------------------------------------------------------
__global__ __launch_bounds__(256) void deg_kernel(
    const int* __restrict__ cols, const float* __restrict__ ew,
    float* __restrict__ deg, int E) {
  int e = blockIdx.x * 256 + threadIdx.x;
  if (e >= E) return;
  atomicAdd(deg + cols[e], ew[e]);
}

// Pass 2: bucket scatter (fixed 64-slot rows), normalized weights.
// fill pre-zeroed. Rows Poisson(16): P(deg>64) ~ 1e-18, clamp deterministic.
__global__ __launch_bounds__(256) void scatter_kernel(
    const int* __restrict__ rows, const int* __restrict__ cols,
    const float* __restrict__ ew, const float* __restrict__ deg,
    int* __restrict__ fill, int* __restrict__ col_s, float* __restrict__ w_s,
    int E) {
  int e = blockIdx.x * 256 + threadIdx.x;
  if (e >= E) return;
  int r = rows[e], c = cols[e];
  float w = ew[e] / fmaxf(deg[c], EPSW);
  int pos = atomicAdd(fill + r, 1);
  if (pos < BUCKET) {
    col_s[(r << LBUCK) + pos] = c;
    w_s[(r << LBUCK) + pos] = w;
  }
}

// ---------------------------------------------------------------------------
// M2 = M*M from buckets. One wave per row, dense fp32 LDS accumulator
// (swizzled). Inner gather: 4 edges concurrently in 16-lane groups (__shfl),
// fill[] vector-prefetched. Fused diag1 (self-loops, wave reduce) + diag2.
// ---------------------------------------------------------------------------
__global__ __launch_bounds__(64) void m2_csr_kernel(
    const int* __restrict__ fill, const int* __restrict__ col_s,
    const float* __restrict__ w_s, ushort* __restrict__ dst,
    float* __restrict__ diags) {
  int i = blockIdx.x;
  int tid = threadIdx.x;
  __shared__ float acc[NN];
  float4 z4 = make_float4(0.f, 0.f, 0.f, 0.f);
#pragma unroll
  for (int k = 0; k < 16; ++k) *(float4*)(acc + k * 256 + tid * 4) = z4;
  int cnt = min(fill[i], BUCKET);
  __syncthreads();
  int myc = 0, fj = 0;
  float myw = 0.f;
  if (tid < cnt) {
    myc = col_s[(i << LBUCK) + tid];
    myw = w_s[(i << LBUCK) + tid];
    fj = min(fill[myc], BUCKET);  // parallel vector prefetch
  }
  // diag1 = sum of self-loop weights (handles duplicates)
  float sl = (tid < cnt && myc == i) ? myw : 0.f;
#pragma unroll
  for (int o = 32; o; o >>= 1) sl += __shfl_down(sl, o);
  if (tid == 0) diags[i] = sl;

  int g = tid >> 4, f0 = tid & 15;
  for (int e = 0; e < cnt; e += 4) {
    int idx = e + g;
    bool v = idx < cnt;
    int srcl = v ? idx : 0;
    int j = __shfl(myc, srcl);
    float we = __shfl(myw, srcl);
    int fc = __shfl(fj, srcl);
    if (v) {
      for (int f = f0; f < fc; f += 16)
        atomicAdd(acc + sphys(col_s[(j << LBUCK) + f]),
                  we * w_s[(j << LBUCK) + f]);
    }
  }
  __syncthreads();
  if (tid == 0) diags[NN + i] = acc[sphys(i)];
#pragma unroll
  for (int p = 0; p < 8; ++p) {
    int c = p * SLABW + tid * 8;
    int ph = sphys(c);
    float4 lo = *(const float4*)(acc + ph);
    float4 hi = *(const float4*)(acc + ph + 4);
    uint4v o;
    o.x = bf16rn(lo.x) | (bf16rn(lo.y) << 16);
    o.y = bf16rn(lo.z) | (bf16rn(lo.w) << 16);
    o.z = bf16rn(hi.x) | (bf16rn(hi.y) << 16);
    o.w = bf16rn(hi.z) | (bf16rn(hi.w) << 16);
    *(uint4v*)(dst + (size_t)p * SLAB_ELEMS + (size_t)i * SLABW + tid * 8) = o;
  }
}

// ---------------------------------------------------------------------------
// SpMM: 256-thr blocks = 4 waves x 4 rows, same slab (XCD L2 affinity).
// Per-wave private LDS edge staging (no barriers). 8/4/1-deep batches
// (proven round-8 config: ~23 us, VGPR stays occupancy-friendly).
// ---------------------------------------------------------------------------
#define FMA8(u, wv)                                          \
  do {                                                       \
    f32x2 w2_ = {(wv), (wv)};                                \
    _Pragma("unroll") for (int q = 0; q < 4; ++q) {          \
      f32x2 p_;                                              \
      p_.x = __uint_as_float((u)[q] << 16);                  \
      p_.y = __uint_as_float((u)[q] & 0xFFFF0000u);          \
      acc2[q] = p_ * w2_ + acc2[q];                          \
    }                                                        \
  } while (0)

__global__ __launch_bounds__(256) void spmm_kernel(
    const ushort* __restrict__ src, ushort* __restrict__ dst,
    const int* __restrict__ fill, const int* __restrict__ col_s,
    const float* __restrict__ w_s, float* __restrict__ diags, int tIdx) {
  int b = blockIdx.x;
  int slab = b & (NSLAB - 1);
  int wv = threadIdx.x >> 6;
  int lane = threadIdx.x & 63;
  int i = ((b >> 3) << 2) | wv;
  int cnt = min(fill[i], BUCKET);
  __shared__ int sc_all[4][64];
  __shared__ float sw_all[4][64];
  int* sc = sc_all[wv];
  float* sw = sw_all[wv];
  f32x2 acc2[4];
#pragma unroll
  for (int q = 0; q < 4; ++q) acc2[q] = (f32x2){0.f, 0.f};
  const ushort* sbase = src + (size_t)slab * SLAB_ELEMS + lane * 8;

  if (lane < cnt) {
    sc[lane] = col_s[(i << LBUCK) + lane];
    sw[lane] = w_s[(i << LBUCK) + lane];
  }
  // no __syncthreads: producer wave == consumer wave (lgkmcnt ordering)
  int k = 0;
  for (; k + 8 <= cnt; k += 8) {
    uint4v u0 = *(const uint4v*)(sbase + ((size_t)sc[k]     << LSLAB));
    uint4v u1 = *(const uint4v*)(sbase + ((size_t)sc[k + 1] << LSLAB));
    uint4v u2 = *(const uint4v*)(sbase + ((size_t)sc[k + 2] << LSLAB));
    uint4v u3 = *(const uint4v*)(sbase + ((size_t)sc[k + 3] << LSLAB));
    uint4v u4 = *(const uint4v*)(sbase + ((size_t)sc[k + 4] << LSLAB));
    uint4v u5 = *(const uint4v*)(sbase + ((size_t)sc[k + 5] << LSLAB));
    uint4v u6 = *(const uint4v*)(sbase + ((size_t)sc[k + 6] << LSLAB));
    uint4v u7 = *(const uint4v*)(sbase + ((size_t)sc[k + 7] << LSLAB));
    float w0 = sw[k], w1 = sw[k + 1], w2 = sw[k + 2], w3 = sw[k + 3];
    float w4 = sw[k + 4], w5 = sw[k + 5], w6 = sw[k + 6], w7 = sw[k + 7];
    FMA8(u0, w0); FMA8(u1, w1); FMA8(u2, w2); FMA8(u3, w3);
    FMA8(u4, w4); FMA8(u5, w5); FMA8(u6, w6); FMA8(u7, w7);
  }
  for (; k + 4 <= cnt; k += 4) {
    uint4v u0 = *(const uint4v*)(sbase + ((size_t)sc[k]     << LSLAB));
    uint4v u1 = *(const uint4v*)(sbase + ((size_t)sc[k + 1] << LSLAB));
    uint4v u2 = *(const uint4v*)(sbase + ((size_t)sc[k + 2] << LSLAB));
    uint4v u3 = *(const uint4v*)(sbase + ((size_t)sc[k + 3] << LSLAB));
    float w0 = sw[k], w1 = sw[k + 1], w2 = sw[k + 2], w3 = sw[k + 3];
    FMA8(u0, w0); FMA8(u1, w1); FMA8(u2, w2); FMA8(u3, w3);
  }
  for (; k < cnt; ++k) {
    uint4v u = *(const uint4v*)(sbase + ((size_t)sc[k] << LSLAB));
    float w = sw[k];
    FMA8(u, w);
  }

  uint4v o;
#pragma unroll
  for (int q = 0; q < 4; ++q)
    o[q] = bf16rn(acc2[q].x) | (bf16rn(acc2[q].y) << 16);
  *(uint4v*)(dst + (size_t)slab * SLAB_ELEMS + (size_t)i * SLABW + lane * 8) = o;

  if ((i >> LSLAB) == slab) {
    int lc = i & (SLABW - 1);
    if ((lc >> 3) == lane) {
      int m = lc & 7;
      f32x2 pr = acc2[m >> 1];
      float v = (m & 1) ? pr.y : pr.x;
      diags[tIdx * NN + i] = v;
    }
  }
}

// ---------------------------------------------------------------------------
// Trace products -> PARTIALS (no atomics): part[(v*8+jc)*NN + gi].
// diag5 = <M2,M3^T>, diag6 = <M3,M3^T>, diag7 = <M3,M4^T>, diag8 = <M4,M4^T>.
// ---------------------------------------------------------------------------
__device__ __forceinline__ size_t slab_addr(int row, int col) {
  return ((size_t)(col >> LSLAB)) * SLAB_ELEMS + (size_t)row * SLABW + (col & (SLABW - 1));
}
__device__ __forceinline__ float elem8(uint4v lo, uint4v hi, int c) {
  uint32 u = (c < 8) ? lo[(c & 7) >> 1] : hi[(c & 7) >> 1];
  return __uint_as_float((c & 1) ? (u & 0xFFFF0000u) : (u << 16));
}

__global__ __launch_bounds__(256) void trace_kernel(
    const ushort* __restrict__ M2, const ushort* __restrict__ M3,
    const ushort* __restrict__ M4, float* __restrict__ part) {
  int bid = blockIdx.x;
  int bi = bid >> 3, jc = bid & 7;
  int tid = threadIdx.x;
  __shared__ ushort b3[64 * 64], b4[64 * 64];
  __shared__ float red[4][4][64];
  int lr = tid >> 2, lc0 = (tid & 3) * 16;
  int r = tid & 63, jq = tid >> 6;
  float s5 = 0.f, s6 = 0.f, s7 = 0.f, s8 = 0.f;

  for (int it = 0; it < 8; ++it) {
    int bj = jc * 8 + it;
    {
      int gj = bj * 64 + lr;
      int gc = bi * 64 + lc0;
      size_t base = slab_addr(gj, gc);
      uint4v v3a = *(const uint4v*)(M3 + base);
      uint4v v3b = *(const uint4v*)(M3 + base + 8);
      uint4v v4a = *(const uint4v*)(M4 + base);
      uint4v v4b = *(const uint4v*)(M4 + base + 8);
      int cb0 = (lc0 >> 3) ^ (lr & 7);
      int cb1 = ((lc0 >> 3) + 1) ^ (lr & 7);
      *(uint4v*)(b3 + lr * 64 + cb0 * 8) = v3a;
      *(uint4v*)(b3 + lr * 64 + cb1 * 8) = v3b;
      *(uint4v*)(b4 + lr * 64 + cb0 * 8) = v4a;
      *(uint4v*)(b4 + lr * 64 + cb1 * 8) = v4b;
    }
    __syncthreads();
    int gi = bi * 64 + r;
    int gc0 = bj * 64 + jq * 16;
    size_t abase = slab_addr(gi, gc0);
    uint4v a2a = *(const uint4v*)(M2 + abase);
    uint4v a2b = *(const uint4v*)(M2 + abase + 8);
    uint4v a3a = *(const uint4v*)(M3 + abase);
    uint4v a3b = *(const uint4v*)(M3 + abase + 8);
    uint4v a4a = *(const uint4v*)(M4 + abase);
    uint4v a4b = *(const uint4v*)(M4 + abase + 8);
#pragma unroll
    for (int c = 0; c < 16; ++c) {
      int jj = jq * 16 + c;
      int idx = jj * 64 + ((((r >> 3) ^ (jj & 7)) << 3) | (r & 7));
      float bv3 = bf2f(b3[idx]);
      float bv4 = bf2f(b4[idx]);
      float av2 = elem8(a2a, a2b, c);
      float av3 = elem8(a3a, a3b, c);
      float av4 = elem8(a4a, a4b, c);
      s5 += av2 * bv3;
      s6 += av3 * bv3;
      s7 += av3 * bv4;
      s8 += av4 * bv4;
    }
    __syncthreads();
  }
  red[0][jq][r] = s5;
  red[1][jq][r] = s6;
  red[2][jq][r] = s7;
  red[3][jq][r] = s8;
  __syncthreads();
  if (tid < 64) {
    int gi = bi * 64 + tid;
#pragma unroll
    for (int v = 0; v < 4; ++v) {
      float s = red[v][0][tid] + red[v][1][tid] + red[v][2][tid] + red[v][3][tid];
      part[((size_t)v * 8 + jc) * NN + gi] = s;
    }
  }
}

// ---------------------------------------------------------------------------
// Finalize: X = [ones, diag_1..diag_8], standardize each column (ddof=0).
// k<=4 read diags rows 0..3; k>=5 reduce 8 trace partials.
// ---------------------------------------------------------------------------
__global__ __launch_bounds__(256) void finalize_kernel(
    const float* __restrict__ diags, const float* __restrict__ part,
    float* __restrict__ out) {
  int k = blockIdx.x;  // 0..8
  int tid = threadIdx.x;
  float vals[16];
  float sum = 0.f, sq = 0.f;
#pragma unroll
  for (int j = 0; j < 16; ++j) {
    int i = j * 256 + tid;
    float v;
    if (k == 0) {
      v = 1.0f;
    } else if (k <= 4) {
      v = diags[(size_t)(k - 1) * NN + i];
    } else {
      v = 0.f;
      const float* p = part + (size_t)(k - 5) * 8 * NN + i;
#pragma unroll
      for (int jc = 0; jc < 8; ++jc) v += p[(size_t)jc * NN];
    }
    vals[j] = v;
    sum += v;
    sq += v * v;
  }
#pragma unroll
  for (int off = 32; off; off >>= 1) {
    sum += __shfl_down(sum, off);
    sq += __shfl_down(sq, off);
  }
  __shared__ float s0[4], s1[4];
  __shared__ float smean, sinv;
  int wid = tid >> 6, lane = tid & 63;
  if (lane == 0) { s0[wid] = sum; s1[wid] = sq; }
  __syncthreads();
  if (tid == 0) {
    float S = s0[0] + s0[1] + s0[2] + s0[3];
    float Q = s1[0] + s1[1] + s1[2] + s1[3];
    float mean = S / (float)NN;
    float var = Q / (float)NN - mean * mean;
    var = fmaxf(var, 0.f);
    float sd = fmaxf(sqrtf(var), 1e-6f);
    smean = mean;
    sinv = 1.f / sd;
  }
  __syncthreads();
#pragma unroll
  for (int j = 0; j < 16; ++j) {
    int i = j * 256 + tid;
    out[i * (TSTEPS + 1) + k] = (vals[j] - smean) * sinv;
  }
}

// ---------------------------------------------------------------------------
// Host driver: 8 graph nodes.
// ---------------------------------------------------------------------------
extern "C" void kernel_launch(void* const* d_in, const int* in_sizes, int n_in,
                              void* d_out, int out_size, void* d_ws, size_t ws_size,
                              hipStream_t stream) {
  const int* ei = (const int*)d_in[0];
  const float* ew = (const float*)d_in[1];
  int E = in_sizes[1];
  const int* rows = ei;
  const int* cols = ei + E;

  char* ws = (char*)d_ws;
  size_t off = 0;
  auto alloc = [&](size_t bytes) {
    void* p = ws + off;
    off = (off + bytes + 255) & ~(size_t)255;
    return p;
  };
  // contiguous zero region: deg | fill (one tiny memset)
  float* deg   = (float*)alloc(NN * 4);
  int*   fill  = (int*)alloc(NN * 4);
  size_t zbytes = off;
  float* diags = (float*)alloc((size_t)4 * NN * 4);       // rows 0..3 (t=1..4)
  float* part  = (float*)alloc((size_t)4 * 8 * NN * 4);   // trace partials
  int*   col_s = (int*)alloc((size_t)NN * BUCKET * 4);
  float* w_s   = (float*)alloc((size_t)NN * BUCKET * 4);
  ushort* bufA = (ushort*)alloc((size_t)NN * NN * 2);  // M2
  ushort* bufB = (ushort*)alloc((size_t)NN * NN * 2);  // M3
  ushort* bufC = (ushort*)alloc((size_t)NN * NN * 2);  // M4

  hipMemsetAsync(deg, 0, zbytes, stream);

  int eb = (E + 255) / 256;
  deg_kernel<<<eb, 256, 0, stream>>>(cols, ew, deg, E);
  scatter_kernel<<<eb, 256, 0, stream>>>(rows, cols, ew, deg, fill, col_s, w_s, E);

  m2_csr_kernel<<<NN, 64, 0, stream>>>(fill, col_s, w_s, bufA, diags);
  spmm_kernel<<<(NN / 4) * NSLAB, 256, 0, stream>>>(bufA, bufB, fill, col_s, w_s, diags, 2);
  spmm_kernel<<<(NN / 4) * NSLAB, 256, 0, stream>>>(bufB, bufC, fill, col_s, w_s, diags, 3);
  trace_kernel<<<512, 256, 0, stream>>>(bufA, bufB, bufC, part);

  finalize_kernel<<<TSTEPS + 1, 256, 0, stream>>>(diags, part, (float*)d_out);
}